// Round 1
// baseline (399.734 us; speedup 1.0000x reference)
//
#include <hip/hip_runtime.h>
#include <math.h>

#define DIN 512
#define DOUT 256
#define NEG_SLOPE 0.01f

// ---------------- GEMM: h = x @ W  (fp32, vector ALU) ----------------
// BM=128, BN=128, BK=16, 256 threads, 8x8 per thread (two 4-wide groups each dim)
__global__ __launch_bounds__(256) void gemm_h(const float* __restrict__ A,
                                              const float* __restrict__ B,
                                              float* __restrict__ C, int M) {
    const int K = DIN, Nn = DOUT;
    __shared__ float As[16][128];  // [k][m] transposed
    __shared__ float Bs[16][128];  // [k][n]

    int tid = threadIdx.x;
    int tx = tid & 15;       // 0..15 -> col groups
    int ty = tid >> 4;       // 0..15 -> row groups
    int m0 = blockIdx.x * 128;
    int n0 = blockIdx.y * 128;

    int lr = tid >> 2;           // 0..63 row for A load
    int lk = (tid & 3) << 2;     // k offset 0,4,8,12

    float4 acc[2][2][4];
#pragma unroll
    for (int i = 0; i < 2; i++)
#pragma unroll
        for (int j = 0; j < 2; j++)
#pragma unroll
            for (int r = 0; r < 4; r++) acc[i][j][r] = make_float4(0.f, 0.f, 0.f, 0.f);

    for (int k0 = 0; k0 < K; k0 += 16) {
        int r0 = m0 + lr;       if (r0 >= M) r0 = M - 1;
        int r1 = m0 + lr + 64;  if (r1 >= M) r1 = M - 1;
        float4 av0 = *(const float4*)(A + (size_t)r0 * K + k0 + lk);
        float4 av1 = *(const float4*)(A + (size_t)r1 * K + k0 + lk);
        float4 bv0 = *(const float4*)(B + (size_t)(k0 + ty) * Nn + n0 + tx * 4);
        float4 bv1 = *(const float4*)(B + (size_t)(k0 + ty) * Nn + n0 + tx * 4 + 64);
        __syncthreads();
        As[lk + 0][lr] = av0.x; As[lk + 1][lr] = av0.y; As[lk + 2][lr] = av0.z; As[lk + 3][lr] = av0.w;
        As[lk + 0][lr + 64] = av1.x; As[lk + 1][lr + 64] = av1.y; As[lk + 2][lr + 64] = av1.z; As[lk + 3][lr + 64] = av1.w;
        *(float4*)&Bs[ty][tx * 4] = bv0;
        *(float4*)&Bs[ty][tx * 4 + 64] = bv1;
        __syncthreads();
#pragma unroll
        for (int kk = 0; kk < 16; kk++) {
            float4 a0 = *(const float4*)&As[kk][ty * 4];
            float4 a1 = *(const float4*)&As[kk][ty * 4 + 64];
            float4 b0 = *(const float4*)&Bs[kk][tx * 4];
            float4 b1 = *(const float4*)&Bs[kk][tx * 4 + 64];
            float ar[2][4] = {{a0.x, a0.y, a0.z, a0.w}, {a1.x, a1.y, a1.z, a1.w}};
            float4 bb[2] = {b0, b1};
#pragma unroll
            for (int i = 0; i < 2; i++)
#pragma unroll
                for (int r = 0; r < 4; r++) {
                    float av = ar[i][r];
#pragma unroll
                    for (int j = 0; j < 2; j++) {
                        acc[i][j][r].x += av * bb[j].x;
                        acc[i][j][r].y += av * bb[j].y;
                        acc[i][j][r].z += av * bb[j].z;
                        acc[i][j][r].w += av * bb[j].w;
                    }
                }
        }
    }
#pragma unroll
    for (int i = 0; i < 2; i++)
#pragma unroll
        for (int r = 0; r < 4; r++) {
            int row = m0 + i * 64 + ty * 4 + r;
            if (row < M) {
#pragma unroll
                for (int j = 0; j < 2; j++) {
                    *(float4*)(C + (size_t)row * Nn + n0 + j * 64 + tx * 4) = acc[i][j][r];
                }
            }
        }
}

// ---------------- per-node score dots: s_src = h @ a[:256], s_dst = h @ a[256:] --------
__global__ void node_scores(const float* __restrict__ h, const float* __restrict__ a,
                            float* __restrict__ s_src, float* __restrict__ s_dst, int N) {
    int gt = blockIdx.x * blockDim.x + threadIdx.x;
    int w = gt >> 6;
    int lane = threadIdx.x & 63;
    if (w >= N) return;
    float4 hv = *(const float4*)(h + (size_t)w * DOUT + lane * 4);
    float4 as = *(const float4*)(a + lane * 4);
    float4 ad = *(const float4*)(a + DOUT + lane * 4);
    float ss = hv.x * as.x + hv.y * as.y + hv.z * as.z + hv.w * as.w;
    float sd = hv.x * ad.x + hv.y * ad.y + hv.z * ad.z + hv.w * ad.w;
#pragma unroll
    for (int off = 32; off > 0; off >>= 1) {
        ss += __shfl_xor(ss, off);
        sd += __shfl_xor(sd, off);
    }
    if (lane == 0) { s_src[w] = ss; s_dst[w] = sd; }
}

// ---------------- degree histogram ----------------
__global__ void zero_int(int* __restrict__ p, int n) {
    int i = blockIdx.x * blockDim.x + threadIdx.x;
    if (i < n) p[i] = 0;
}

__global__ void hist_k(const int* __restrict__ src, int* __restrict__ deg, int E) {
    int i = blockIdx.x * blockDim.x + threadIdx.x;
    if (i < E) atomicAdd(&deg[src[i]], 1);
}

// ---------------- exclusive scan (single block, chunked Hillis-Steele) ----------------
__global__ __launch_bounds__(1024) void scan_k(const int* __restrict__ deg, int* __restrict__ rowptr,
                                               int* __restrict__ cursor, int N) {
    __shared__ int sm[1024];
    __shared__ int carry_s;
    int t = threadIdx.x;
    if (t == 0) carry_s = 0;
    __syncthreads();
    for (int base = 0; base < N; base += 1024) {
        int idx = base + t;
        int v = (idx < N) ? deg[idx] : 0;
        sm[t] = v;
        __syncthreads();
        int x = v;
#pragma unroll
        for (int off = 1; off < 1024; off <<= 1) {
            int y = (t >= off) ? sm[t - off] : 0;
            __syncthreads();
            x += y;
            sm[t] = x;
            __syncthreads();
        }
        int total_prev = carry_s;
        int excl = total_prev + x - v;
        if (idx < N) { rowptr[idx] = excl; cursor[idx] = excl; }
        __syncthreads();
        if (t == 1023) carry_s = total_prev + x;
        __syncthreads();
    }
    if (t == 0) rowptr[N] = carry_s;
}

// ---------------- edge scoring + CSR scatter ----------------
__global__ void edge_k(const int* __restrict__ src, const int* __restrict__ dst,
                       const float* __restrict__ s_src, const float* __restrict__ s_dst,
                       int* __restrict__ cursor, int* __restrict__ csr_dst,
                       float* __restrict__ csr_ev, int E) {
    int i = blockIdx.x * blockDim.x + threadIdx.x;
    if (i >= E) return;
    int s = src[i], d = dst[i];
    float sc = s_src[s] + s_dst[d];
    float lrv = sc > 0.f ? sc : NEG_SLOPE * sc;
    float ev = expf(-lrv);
    int pos = atomicAdd(&cursor[s], 1);
    csr_dst[pos] = d;
    csr_ev[pos] = ev;
}

// ---------------- per-row gather SpMM + div + ELU ----------------
__global__ void gather_k(const float* __restrict__ h, const int* __restrict__ rowptr,
                         const int* __restrict__ csr_dst, const float* __restrict__ csr_ev,
                         float* __restrict__ out, int N) {
    int gt = blockIdx.x * blockDim.x + threadIdx.x;
    int w = gt >> 6;
    int lane = threadIdx.x & 63;
    if (w >= N) return;
    int s0 = rowptr[w], s1 = rowptr[w + 1];
    float4 acc = make_float4(0.f, 0.f, 0.f, 0.f);
    float rs = 0.f;
    for (int j = s0; j < s1; j++) {
        int d = csr_dst[j];
        float ev = csr_ev[j];
        float4 hv = *(const float4*)(h + (size_t)d * DOUT + lane * 4);
        acc.x += ev * hv.x;
        acc.y += ev * hv.y;
        acc.z += ev * hv.z;
        acc.w += ev * hv.w;
        rs += ev;
    }
    float inv = 1.f / rs;
    float4 v;
    v.x = acc.x * inv; v.y = acc.y * inv; v.z = acc.z * inv; v.w = acc.w * inv;
    v.x = v.x > 0.f ? v.x : expf(v.x) - 1.f;
    v.y = v.y > 0.f ? v.y : expf(v.y) - 1.f;
    v.z = v.z > 0.f ? v.z : expf(v.z) - 1.f;
    v.w = v.w > 0.f ? v.w : expf(v.w) - 1.f;
    *(float4*)(out + (size_t)w * DOUT + lane * 4) = v;
}

extern "C" void kernel_launch(void* const* d_in, const int* in_sizes, int n_in,
                              void* d_out, int out_size, void* d_ws, size_t ws_size,
                              hipStream_t stream) {
    const float* x = (const float*)d_in[0];
    const float* W = (const float*)d_in[1];
    const float* a = (const float*)d_in[2];
    const int* edge_src = (const int*)d_in[3];
    const int* edge_dst = (const int*)d_in[4];

    const int N = in_sizes[0] / DIN;
    const int E = in_sizes[3];

    // workspace layout (16B-aligned regions)
    char* ws = (char*)d_ws;
    size_t off = 0;
    auto alloc = [&](size_t bytes) {
        void* p = ws + off;
        off += (bytes + 15) & ~(size_t)15;
        return p;
    };
    float* h = (float*)alloc((size_t)N * DOUT * 4);
    int* rowptr = (int*)alloc((size_t)(N + 1) * 4);
    int* deg = (int*)alloc((size_t)N * 4);
    int* cursor = (int*)alloc((size_t)N * 4);
    float* s_src = (float*)alloc((size_t)N * 4);
    float* s_dst = (float*)alloc((size_t)N * 4);
    int* csr_dst = (int*)alloc((size_t)E * 4);
    float* csr_ev = (float*)alloc((size_t)E * 4);
    (void)ws_size;

    float* out = (float*)d_out;

    // 1) h = x @ W
    dim3 ggrid((N + 127) / 128, DOUT / 128);
    gemm_h<<<ggrid, 256, 0, stream>>>(x, W, h, N);

    // 2) zero degree
    zero_int<<<(N + 255) / 256, 256, 0, stream>>>(deg, N);

    // 3) per-node scores
    node_scores<<<(N + 3) / 4, 256, 0, stream>>>(h, a, s_src, s_dst, N);

    // 4) histogram
    hist_k<<<(E + 255) / 256, 256, 0, stream>>>(edge_src, deg, E);

    // 5) scan -> rowptr, cursor
    scan_k<<<1, 1024, 0, stream>>>(deg, rowptr, cursor, N);

    // 6) edge scores + CSR scatter
    edge_k<<<(E + 255) / 256, 256, 0, stream>>>(edge_src, edge_dst, s_src, s_dst,
                                                cursor, csr_dst, csr_ev, E);

    // 7) gather + normalize + ELU
    gather_k<<<(N + 3) / 4, 256, 0, stream>>>(h, rowptr, csr_dst, csr_ev, out, N);
}

// Round 2
// 160.913 us; speedup vs baseline: 2.4842x; 2.4842x over previous
//
#include <hip/hip_runtime.h>
#include <math.h>

#define DIN 512
#define DOUT 256
#define NEG_SLOPE 0.01f
#define BM 128
#define BK 32

typedef __attribute__((ext_vector_type(8))) short bf16x8;
typedef __attribute__((ext_vector_type(4))) float f32x4;
typedef __attribute__((ext_vector_type(4))) unsigned int u32x4;

__device__ __forceinline__ unsigned short f2bf(float f) {
    unsigned int u = __float_as_uint(f);
    unsigned int r = (u + 0x7FFFu + ((u >> 16) & 1u)) >> 16;
    return (unsigned short)r;
}
__device__ __forceinline__ float bf2f(unsigned short u) {
    return __uint_as_float(((unsigned int)u) << 16);
}
__device__ __forceinline__ unsigned int cvtpk(float lo, float hi) {
    unsigned int r;
    asm("v_cvt_pk_bf16_f32 %0, %1, %2" : "=v"(r) : "v"(lo), "v"(hi));
    return r;
}
__device__ __forceinline__ void gload16(const void* g, void* l) {
    __builtin_amdgcn_global_load_lds(
        (const __attribute__((address_space(1))) void*)g,
        (__attribute__((address_space(3))) void*)l, 16, 0, 0);
}

// ---------------- W -> Wt (bf16, transposed [DOUT][DIN]) ----------------
__global__ void wt_convert(const float* __restrict__ W, unsigned short* __restrict__ Wt) {
    int t = blockIdx.x * blockDim.x + threadIdx.x;
    if (t >= DIN * DOUT) return;
    int k = t >> 8;        // 0..511
    int c = t & 255;       // 0..255
    Wt[c * DIN + k] = f2bf(W[t]);
}

// ---------------- GEMM: hb = bf16( x @ W )  via MFMA ----------------
// 512 threads = 8 waves (2 row-groups x 4 col-groups), tile 128x256, BK=32.
// A staged fp32 (16KB/buf) w/ 8-slot XOR swizzle; B staged bf16 (16KB/buf) w/ 4-slot swizzle.
__global__ __launch_bounds__(512) void gemm_k(const float* __restrict__ x,
                                              const unsigned short* __restrict__ Wt,
                                              unsigned short* __restrict__ hb, int M) {
    __shared__ unsigned char lds[65536];  // A0 @0, A1 @16K, B0 @32K, B1 @48K
    const int t = threadIdx.x;
    const int lane = t & 63;
    const int wv = t >> 6;
    const int wr = wv >> 2;   // 0..1
    const int wc = wv & 3;    // 0..3
    const int m0 = blockIdx.x * BM;

    f32x4 acc[4][4] = {};

    auto stage = [&](int bb, int k0) {
#pragma unroll
        for (int ci = 0; ci < 4; ++ci) {
            int c = wv * 4 + ci;
            if (c < 16) {
                // A chunk: rows 8c..8c+7, 8 fp32-quad slots per row
                int row = c * 8 + (lane >> 3);
                int q = (lane & 7) ^ (lane >> 3);  // k-quad held in linear slot (lane&7)
                int rg = m0 + row; if (rg >= M) rg = M - 1;
                const float* src = x + (size_t)rg * DIN + k0 + q * 4;
                gload16(src, lds + bb * 16384 + c * 1024);
            } else {
                int cb = c - 16;
                // B chunk: cols 16cb..16cb+15, 4 bf16-octet slots per col
                int col = cb * 16 + (lane >> 2);
                int s = lane & 3;
                int sw = (col ^ (col >> 2)) & 3;
                int q8 = s ^ sw;
                const unsigned short* src = Wt + (size_t)col * DIN + k0 + q8 * 8;
                gload16(src, lds + 32768 + bb * 16384 + cb * 1024);
            }
        }
    };

    auto compute = [&](int bb) {
        const unsigned char* Ab = lds + bb * 16384;
        const unsigned char* Bb = lds + 32768 + bb * 16384;
        const int g = lane >> 4;
        bf16x8 af[4];
#pragma unroll
        for (int rf = 0; rf < 4; ++rf) {
            int row = wr * 64 + rf * 16 + (lane & 15);
            int r7 = row & 7;
            f32x4 v0 = *(const f32x4*)(Ab + row * 128 + (((2 * g) ^ r7) * 16));
            f32x4 v1 = *(const f32x4*)(Ab + row * 128 + (((2 * g + 1) ^ r7) * 16));
            u32x4 p;
            p.x = cvtpk(v0.x, v0.y);
            p.y = cvtpk(v0.z, v0.w);
            p.z = cvtpk(v1.x, v1.y);
            p.w = cvtpk(v1.z, v1.w);
            af[rf] = *(bf16x8*)&p;
        }
        bf16x8 bfr[4];
#pragma unroll
        for (int cf = 0; cf < 4; ++cf) {
            int col = wc * 64 + cf * 16 + (lane & 15);
            int sw = (col ^ (col >> 2)) & 3;
            bfr[cf] = *(const bf16x8*)(Bb + col * 64 + ((g ^ sw) * 16));
        }
#pragma unroll
        for (int rf = 0; rf < 4; ++rf)
#pragma unroll
            for (int cf = 0; cf < 4; ++cf)
                acc[rf][cf] = __builtin_amdgcn_mfma_f32_16x16x32_bf16(af[rf], bfr[cf], acc[rf][cf], 0, 0, 0);
    };

    stage(0, 0);
    for (int ts = 0; ts < DIN / BK; ++ts) {
        if (ts < DIN / BK - 1) stage((ts + 1) & 1, (ts + 1) * BK);
        __syncthreads();
        compute(ts & 1);
        __syncthreads();
    }

#pragma unroll
    for (int rf = 0; rf < 4; ++rf) {
#pragma unroll
        for (int j = 0; j < 4; ++j) {
            int row = m0 + wr * 64 + rf * 16 + (lane >> 4) * 4 + j;
            if (row < M) {
#pragma unroll
                for (int cf = 0; cf < 4; ++cf) {
                    int col = wc * 64 + cf * 16 + (lane & 15);
                    hb[(size_t)row * DOUT + col] = f2bf(acc[rf][cf][j]);
                }
            }
        }
    }
}

// ---------------- per-node score dots (bf16 h) ----------------
__global__ void node_scores(const unsigned short* __restrict__ hb, const float* __restrict__ a,
                            float* __restrict__ s_src, float* __restrict__ s_dst, int N) {
    int gt = blockIdx.x * blockDim.x + threadIdx.x;
    int w = gt >> 6;
    int lane = threadIdx.x & 63;
    if (w >= N) return;
    ushort4 hv = *(const ushort4*)(hb + (size_t)w * DOUT + lane * 4);
    float4 as = *(const float4*)(a + lane * 4);
    float4 ad = *(const float4*)(a + DOUT + lane * 4);
    float h0 = bf2f(hv.x), h1 = bf2f(hv.y), h2 = bf2f(hv.z), h3 = bf2f(hv.w);
    float ss = h0 * as.x + h1 * as.y + h2 * as.z + h3 * as.w;
    float sd = h0 * ad.x + h1 * ad.y + h2 * ad.z + h3 * ad.w;
#pragma unroll
    for (int off = 32; off > 0; off >>= 1) {
        ss += __shfl_xor(ss, off);
        sd += __shfl_xor(sd, off);
    }
    if (lane == 0) { s_src[w] = ss; s_dst[w] = sd; }
}

// ---------------- degree histogram ----------------
__global__ void zero_int(int* __restrict__ p, int n) {
    int i = blockIdx.x * blockDim.x + threadIdx.x;
    if (i < n) p[i] = 0;
}

__global__ void hist_k(const int* __restrict__ src, int* __restrict__ deg, int E) {
    int i = blockIdx.x * blockDim.x + threadIdx.x;
    if (i < E) atomicAdd(&deg[src[i]], 1);
}

// ---------------- 3-stage scan: blocksum -> top scan -> block rescan ----------------
__global__ __launch_bounds__(256) void block_sum(const int* __restrict__ deg, int* __restrict__ bsum, int N) {
    __shared__ int wsum[4];
    int b = blockIdx.x, t = threadIdx.x;
    int idx = b * 1024 + t * 4;
    int s = 0;
    if (idx + 3 < N) {
        int4 v = *(const int4*)(deg + idx);
        s = v.x + v.y + v.z + v.w;
    } else {
        for (int i = 0; i < 4; i++) if (idx + i < N) s += deg[idx + i];
    }
#pragma unroll
    for (int off = 32; off > 0; off >>= 1) s += __shfl_xor(s, off);
    if ((t & 63) == 0) wsum[t >> 6] = s;
    __syncthreads();
    if (t == 0) bsum[b] = wsum[0] + wsum[1] + wsum[2] + wsum[3];
}

__global__ void scan_tops(const int* __restrict__ bsum, int* __restrict__ boff,
                          int* __restrict__ rowptr, int nb, int N, int E) {
    int t = threadIdx.x;  // single wave of 64
    int v = (t < nb) ? bsum[t] : 0;
    int x = v;
#pragma unroll
    for (int off = 1; off < 64; off <<= 1) {
        int y = __shfl_up(x, off);
        if (t >= off) x += y;
    }
    if (t < nb) boff[t] = x - v;
    if (t == 0) rowptr[N] = E;
}

__global__ __launch_bounds__(256) void scan_blk(const int* __restrict__ deg, const int* __restrict__ boff,
                                                int* __restrict__ rowptr, int* __restrict__ cursor, int N) {
    __shared__ int wsum[4];
    int b = blockIdx.x, t = threadIdx.x;
    int idx = b * 1024 + t * 4;
    int v0 = 0, v1 = 0, v2 = 0, v3 = 0;
    if (idx + 3 < N) {
        int4 v = *(const int4*)(deg + idx);
        v0 = v.x; v1 = v.y; v2 = v.z; v3 = v.w;
    } else if (idx < N) {
        v0 = deg[idx];
        if (idx + 1 < N) v1 = deg[idx + 1];
        if (idx + 2 < N) v2 = deg[idx + 2];
    }
    int s = v0 + v1 + v2 + v3;
    int lane = t & 63, wid = t >> 6;
    int x = s;
#pragma unroll
    for (int off = 1; off < 64; off <<= 1) {
        int y = __shfl_up(x, off);
        if (lane >= off) x += y;
    }
    if (lane == 63) wsum[wid] = x;
    __syncthreads();
    int add = boff[b];
    for (int ww = 0; ww < wid; ++ww) add += wsum[ww];
    int e0 = add + x - s;
    int e1 = e0 + v0, e2 = e1 + v1, e3 = e2 + v2;
    if (idx < N)     { rowptr[idx] = e0;     cursor[idx] = e0; }
    if (idx + 1 < N) { rowptr[idx + 1] = e1; cursor[idx + 1] = e1; }
    if (idx + 2 < N) { rowptr[idx + 2] = e2; cursor[idx + 2] = e2; }
    if (idx + 3 < N) { rowptr[idx + 3] = e3; cursor[idx + 3] = e3; }
}

// ---------------- edge scoring + CSR scatter (packed pair) ----------------
__global__ void edge_k(const int* __restrict__ src, const int* __restrict__ dst,
                       const float* __restrict__ s_src, const float* __restrict__ s_dst,
                       int* __restrict__ cursor, int2* __restrict__ csr, int E) {
    int i = blockIdx.x * blockDim.x + threadIdx.x;
    if (i >= E) return;
    int s = src[i], d = dst[i];
    float sc = s_src[s] + s_dst[d];
    float lrv = sc > 0.f ? sc : NEG_SLOPE * sc;
    float ev = __expf(-lrv);
    int pos = atomicAdd(&cursor[s], 1);
    csr[pos] = make_int2(d, __float_as_int(ev));
}

// ---------------- per-row gather SpMM (bf16 h) + div + ELU ----------------
__global__ __launch_bounds__(256) void gather_k(const unsigned short* __restrict__ hb,
                                                const int* __restrict__ rowptr,
                                                const int2* __restrict__ csr,
                                                float* __restrict__ out, int N) {
    int gt = blockIdx.x * blockDim.x + threadIdx.x;
    int w = gt >> 6;
    int lane = threadIdx.x & 63;
    if (w >= N) return;
    int s0 = rowptr[w], s1 = rowptr[w + 1];
    float a0 = 0.f, a1 = 0.f, a2 = 0.f, a3 = 0.f, rs = 0.f;
    for (int base = s0; base < s1; base += 64) {
        int cnt = min(64, s1 - base);
        int dv = 0; float ev = 0.f;
        if (lane < cnt) {
            int2 p = csr[base + lane];
            dv = p.x; ev = __int_as_float(p.y);
        }
        int jj = 0;
        for (; jj + 4 <= cnt; jj += 4) {
            int d0 = __shfl(dv, jj), d1 = __shfl(dv, jj + 1), d2 = __shfl(dv, jj + 2), d3 = __shfl(dv, jj + 3);
            float e0 = __shfl(ev, jj), e1 = __shfl(ev, jj + 1), e2 = __shfl(ev, jj + 2), e3 = __shfl(ev, jj + 3);
            ushort4 h0 = *(const ushort4*)(hb + (size_t)d0 * DOUT + lane * 4);
            ushort4 h1 = *(const ushort4*)(hb + (size_t)d1 * DOUT + lane * 4);
            ushort4 h2 = *(const ushort4*)(hb + (size_t)d2 * DOUT + lane * 4);
            ushort4 h3 = *(const ushort4*)(hb + (size_t)d3 * DOUT + lane * 4);
            a0 += e0 * bf2f(h0.x) + e1 * bf2f(h1.x) + e2 * bf2f(h2.x) + e3 * bf2f(h3.x);
            a1 += e0 * bf2f(h0.y) + e1 * bf2f(h1.y) + e2 * bf2f(h2.y) + e3 * bf2f(h3.y);
            a2 += e0 * bf2f(h0.z) + e1 * bf2f(h1.z) + e2 * bf2f(h2.z) + e3 * bf2f(h3.z);
            a3 += e0 * bf2f(h0.w) + e1 * bf2f(h1.w) + e2 * bf2f(h2.w) + e3 * bf2f(h3.w);
            rs += e0 + e1 + e2 + e3;
        }
        for (; jj < cnt; ++jj) {
            int d0 = __shfl(dv, jj);
            float e0 = __shfl(ev, jj);
            ushort4 h0 = *(const ushort4*)(hb + (size_t)d0 * DOUT + lane * 4);
            a0 += e0 * bf2f(h0.x);
            a1 += e0 * bf2f(h0.y);
            a2 += e0 * bf2f(h0.z);
            a3 += e0 * bf2f(h0.w);
            rs += e0;
        }
    }
    float inv = 1.f / rs;
    float4 v;
    v.x = a0 * inv; v.y = a1 * inv; v.z = a2 * inv; v.w = a3 * inv;
    v.x = v.x > 0.f ? v.x : __expf(v.x) - 1.f;
    v.y = v.y > 0.f ? v.y : __expf(v.y) - 1.f;
    v.z = v.z > 0.f ? v.z : __expf(v.z) - 1.f;
    v.w = v.w > 0.f ? v.w : __expf(v.w) - 1.f;
    *(float4*)(out + (size_t)w * DOUT + lane * 4) = v;
}

extern "C" void kernel_launch(void* const* d_in, const int* in_sizes, int n_in,
                              void* d_out, int out_size, void* d_ws, size_t ws_size,
                              hipStream_t stream) {
    const float* x = (const float*)d_in[0];
    const float* W = (const float*)d_in[1];
    const float* a = (const float*)d_in[2];
    const int* edge_src = (const int*)d_in[3];
    const int* edge_dst = (const int*)d_in[4];

    const int N = in_sizes[0] / DIN;
    const int E = in_sizes[3];
    const int nb = (N + 1023) / 1024;

    char* ws = (char*)d_ws;
    size_t off = 0;
    auto alloc = [&](size_t bytes) {
        void* p = ws + off;
        off += (bytes + 15) & ~(size_t)15;
        return p;
    };
    unsigned short* hb = (unsigned short*)alloc((size_t)N * DOUT * 2);
    unsigned short* Wt = (unsigned short*)alloc((size_t)DIN * DOUT * 2);
    int* rowptr = (int*)alloc((size_t)(N + 1) * 4);
    int* deg = (int*)alloc((size_t)N * 4);
    int* cursor = (int*)alloc((size_t)N * 4);
    float* s_src = (float*)alloc((size_t)N * 4);
    float* s_dst = (float*)alloc((size_t)N * 4);
    int2* csr = (int2*)alloc((size_t)E * 8);
    int* bsum = (int*)alloc((size_t)nb * 4);
    int* boff = (int*)alloc((size_t)nb * 4);
    (void)ws_size;

    float* out = (float*)d_out;

    wt_convert<<<(DIN * DOUT + 255) / 256, 256, 0, stream>>>(W, Wt);
    gemm_k<<<(N + BM - 1) / BM, 512, 0, stream>>>(x, Wt, hb, N);
    zero_int<<<(N + 255) / 256, 256, 0, stream>>>(deg, N);
    node_scores<<<(N + 3) / 4, 256, 0, stream>>>(hb, a, s_src, s_dst, N);
    hist_k<<<(E + 255) / 256, 256, 0, stream>>>(edge_src, deg, E);
    block_sum<<<nb, 256, 0, stream>>>(deg, bsum, N);
    scan_tops<<<1, 64, 0, stream>>>(bsum, boff, rowptr, nb, N, E);
    scan_blk<<<nb, 256, 0, stream>>>(deg, boff, rowptr, cursor, N);
    edge_k<<<(E + 255) / 256, 256, 0, stream>>>(edge_src, edge_dst, s_src, s_dst,
                                                cursor, csr, E);
    gather_k<<<(N + 3) / 4, 256, 0, stream>>>(hb, rowptr, csr, out, N);
}